// Round 4
// baseline (370.841 us; speedup 1.0000x reference)
//
#include <hip/hip_runtime.h>

#define Nn 50000
#define Rr 16
#define Dd 64
#define Fin 128
#define Ee 100000
#define NE (Rr * Ee)     // 1600000
#define NBKT 782         // ceil(Nn/64) buckets (64 rows each)
#define CB 256           // count/place blocks
#define EPB (NE / CB)    // 6250 edges per block (16 blocks per relation)
#define SCTOT (NBKT * CB)  // 200192 count-matrix entries
#define SC_NB (SCTOT / 256)  // 782 scan blocks
#define NTILE (Nn / 16)  // 3125

typedef __attribute__((ext_vector_type(8))) short short8;
typedef __attribute__((ext_vector_type(4))) float f32x4;
typedef unsigned short ushort_t;

__device__ inline ushort_t f2bf(float x) {
  union { float f; unsigned u; } v; v.f = x;
  unsigned u = v.u;
  return (ushort_t)((u + 0x7FFFu + ((u >> 16) & 1u)) >> 16);  // RNE
}
__device__ inline float bf2f(ushort_t h) {
  union { unsigned u; float f; } v; v.u = ((unsigned)h) << 16; return v.f;
}

// async global->LDS DMA, 16B per lane; lds dest = base + lane*16 (linear),
// global src = per-lane VGPR address. Counted on vmcnt.
__device__ inline void gload_lds16(const void* g, void* l) {
  __builtin_amdgcn_global_load_lds(
      (const __attribute__((address_space(1))) unsigned int*)g,
      (__attribute__((address_space(3))) unsigned int*)l, 16, 0, 0);
}

// ------- fused pre: MFMA init_gemm + convw + LDS-hist bucket count ---------
#define INIT_TILES 3125            // 50000/16
#define INIT_NB 782                // ceil(3125/4)
#define CONVW_NB 512               // 2*16*64*64 / 256
__global__ __launch_bounds__(256) void pre_k(const float* __restrict__ x,
                                             const float* __restrict__ ent,
                                             ushort_t* __restrict__ emb0,
                                             const float* __restrict__ rel,
                                             ushort_t* __restrict__ wbf,
                                             const int* __restrict__ erow,
                                             int* __restrict__ cnt) {
  __shared__ int lh[NBKT];
  int b = blockIdx.x;
  if (b < INIT_NB) {
    int wave = threadIdx.x >> 6, lane = threadIdx.x & 63;
    int nt = lane & 15, quad = lane >> 4;
    int tile = b * 4 + wave;
    if (tile >= INIT_TILES) return;
    const float* xr = x + ((long)tile * 16 + nt) * Fin + quad * 8;
    short8 afrag[4];
#pragma unroll
    for (int ks = 0; ks < 4; ++ks) {
      float4 p0 = *(const float4*)(xr + ks * 32);
      float4 p1 = *(const float4*)(xr + ks * 32 + 4);
      short8 a;
      a[0] = (short)f2bf(p0.x); a[1] = (short)f2bf(p0.y);
      a[2] = (short)f2bf(p0.z); a[3] = (short)f2bf(p0.w);
      a[4] = (short)f2bf(p1.x); a[5] = (short)f2bf(p1.y);
      a[6] = (short)f2bf(p1.z); a[7] = (short)f2bf(p1.w);
      afrag[ks] = a;
    }
    f32x4 acc[4];
#pragma unroll
    for (int dt = 0; dt < 4; ++dt) acc[dt] = (f32x4){0.f, 0.f, 0.f, 0.f};
#pragma unroll
    for (int ks = 0; ks < 4; ++ks) {
#pragma unroll
      for (int dt = 0; dt < 4; ++dt) {
        short8 bfr;
#pragma unroll
        for (int j = 0; j < 8; ++j)
          bfr[j] = (short)f2bf(ent[(unsigned)(ks * 32 + quad * 8 + j) * Dd + dt * 16 + nt]);
        acc[dt] = __builtin_amdgcn_mfma_f32_16x16x32_bf16(afrag[ks], bfr, acc[dt], 0, 0, 0);
      }
    }
#pragma unroll
    for (int dt = 0; dt < 4; ++dt)
#pragma unroll
      for (int reg = 0; reg < 4; ++reg) {
        int row = tile * 16 + quad * 4 + reg;
        emb0[(unsigned)row * Dd + dt * 16 + nt] = f2bf(acc[dt][reg]);
      }
  } else if (b < INIT_NB + CONVW_NB) {
    int i = (b - INIT_NB) * 256 + threadIdx.x;
    wbf[i] = f2bf(rel[i]);
  } else {
    int blk = b - INIT_NB - CONVW_NB;  // 0..CB-1
    int t = threadIdx.x;
    for (int i = t; i < NBKT; i += 256) lh[i] = 0;
    __syncthreads();
    int r = blk >> 4;
    long gbase = (long)r * Ee + (blk & 15) * EPB;
    for (int i = t; i < EPB; i += 256)
      atomicAdd(&lh[erow[gbase + i] >> 6], 1);  // LDS atomics only
    __syncthreads();
    for (int i = t; i < NBKT; i += 256) cnt[i * CB + blk] = lh[i];
  }
}

// ---------------- parallel scan over cnt[200192], bucket-major --------------
__global__ __launch_bounds__(256) void scan1_k(const int* __restrict__ cnt,
                                               int* __restrict__ bsum) {
  __shared__ int ls[256];
  int t = threadIdx.x;
  ls[t] = cnt[blockIdx.x * 256 + t];
  __syncthreads();
  for (int off = 128; off >= 1; off >>= 1) {
    if (t < off) ls[t] += ls[t + off];
    __syncthreads();
  }
  if (t == 0) bsum[blockIdx.x] = ls[0];
}

__global__ __launch_bounds__(1024) void scan2_k(int* __restrict__ bsum) {
  __shared__ int ls[1024];
  int t = threadIdx.x;
  int v = (t < SC_NB) ? bsum[t] : 0;
  ls[t] = v;
  __syncthreads();
  for (int off = 1; off < 1024; off <<= 1) {
    int x = (t >= off) ? ls[t - off] : 0;
    __syncthreads();
    ls[t] += x;
    __syncthreads();
  }
  if (t < SC_NB) bsum[t] = ls[t] - v;  // exclusive
}

__global__ __launch_bounds__(256) void scan3_k(int* __restrict__ cnt,
                                               const int* __restrict__ bsum,
                                               int* __restrict__ cbase,
                                               int* __restrict__ offs) {
  __shared__ int ls[256];
  int t = threadIdx.x, i = blockIdx.x * 256 + t;
  int v = cnt[i];
  ls[t] = v;
  __syncthreads();
  for (int off = 1; off < 256; off <<= 1) {
    int x = (t >= off) ? ls[t - off] : 0;
    __syncthreads();
    ls[t] += x;
    __syncthreads();
  }
  int excl = ls[t] - v + bsum[blockIdx.x];
  cnt[i] = excl;
  if (t == 0) cbase[blockIdx.x] = excl;
  if (i == SCTOT - 1) { cbase[NBKT] = NE; offs[Nn] = NE; }
}

// ------- place: edges -> bucket-grouped ebkt, LDS cursors, block-private ----
__global__ __launch_bounds__(256) void place_k(const int* __restrict__ erow,
                                               const int* __restrict__ ecol,
                                               const float* __restrict__ ev,
                                               const int* __restrict__ base,
                                               uint2* __restrict__ ebkt) {
  __shared__ int lofs[NBKT];
  int blk = blockIdx.x, t = threadIdx.x;
  for (int i = t; i < NBKT; i += 256) lofs[i] = base[i * CB + blk];
  __syncthreads();
  int r = blk >> 4;
  long gbase = (long)r * Ee + (blk & 15) * EPB;
  for (int i = t; i < EPB; i += 256) {
    long idx = gbase + i;
    int row = erow[idx];
    int pos = atomicAdd(&lofs[row >> 6], 1);
    unsigned vb = f2bf(ev[idx]);
    ebkt[pos] = make_uint2(((unsigned)(row & 63) << 4) | (unsigned)r,
                           (vb << 16) | (unsigned)ecol[idx]);
  }
}

// ------- cluster sort: 64-row cluster -> row-contiguous ed2 + offs ---------
__global__ __launch_bounds__(256) void csort_k(const uint2* __restrict__ ebkt,
                                               const int* __restrict__ cbase,
                                               uint2* __restrict__ ed2,
                                               int* __restrict__ offs) {
  __shared__ int lcnt[64], lstart[64], lcur[64];
  int c = blockIdx.x, t = threadIdx.x;
  int s = cbase[c], e = cbase[c + 1];
  if (t < 64) lcnt[t] = 0;
  __syncthreads();
  for (int i = s + t; i < e; i += 256) atomicAdd(&lcnt[ebkt[i].x >> 4], 1);
  __syncthreads();
  if (t == 0) {
    int run = 0;
    for (int rl = 0; rl < 64; ++rl) {
      int cc = lcnt[rl];
      lstart[rl] = run; lcur[rl] = run; run += cc;
    }
  }
  __syncthreads();
  int nrow = Nn - c * 64; if (nrow > 64) nrow = 64;
  if (t < nrow) offs[c * 64 + t] = s + lstart[t];
  for (int i = s + t; i < e; i += 256) {
    uint2 q = ebkt[i];
    int pos = s + atomicAdd(&lcur[q.x >> 4], 1);
    ed2[pos] = make_uint2(q.x & 15u, q.y);
  }
}

// ---------------- gather7: direct B-frag gather, zero LDS -------------------
// Lane (nt,quad) gathers emb[col_{quad*8+j}][dt*16+nt] directly in MFMA
// B-fragment orientation. Z stored transposed as Z[rel][row][d].
__global__ __launch_bounds__(256) void gather7_k(const ushort_t* __restrict__ emb,
                                                 const int* __restrict__ offs,
                                                 const uint2* __restrict__ ed2,
                                                 ushort_t* __restrict__ Z) {
  const int lane = threadIdx.x & 63;
  const int wave = threadIdx.x >> 6;
  const int nt = lane & 15, quad = lane >> 4;
  const int row = blockIdx.x * 4 + wave;
  if (row >= Nn) return;

  int off_l = (lane < 2) ? offs[row + lane] : 0;
  const int base = __shfl(off_l, 0, 64);
  const int len  = __shfl(off_l, 1, 64) - base;

  f32x4 acc[4];
#pragma unroll
  for (int dt = 0; dt < 4; ++dt) acc[dt] = (f32x4){0.f, 0.f, 0.f, 0.f};

  const int qb = quad << 3;  // this quad's 8 edge slots: qb..qb+7
  const ushort_t* embnt = emb + nt;

  union AW { unsigned w[4]; short8 v; };

  for (int c = 0; c < len; c += 32) {
    int p = c + (lane & 31);
    uint2 myed = (p < len) ? ed2[base + p] : make_uint2(0u, 0u);  // pad: rel=0,val=0

    unsigned yw[4][4];  // [dt][pair] packed bf16 pairs for B fragments
    unsigned aw[4];     // packed selector pairs for A fragment
#pragma unroll
    for (int jp = 0; jp < 4; ++jp) {
      unsigned q0 = (unsigned)__shfl((int)myed.y, qb + 2 * jp, 64);
      unsigned q1 = (unsigned)__shfl((int)myed.y, qb + 2 * jp + 1, 64);
      unsigned x0 = (unsigned)__shfl((int)myed.x, qb + 2 * jp, 64);
      unsigned x1 = (unsigned)__shfl((int)myed.x, qb + 2 * jp + 1, 64);
      const ushort_t* e0 = embnt + (q0 & 0xFFFFu) * 64u;
      const ushort_t* e1 = embnt + (q1 & 0xFFFFu) * 64u;
#pragma unroll
      for (int dt = 0; dt < 4; ++dt)
        yw[dt][jp] = (unsigned)e0[dt * 16] | ((unsigned)e1[dt * 16] << 16);
      unsigned t0 = (x0 == (unsigned)nt) ? (q0 >> 16) : 0u;
      unsigned t1 = (x1 == (unsigned)nt) ? (q1 >> 16) : 0u;
      aw[jp] = t0 | (t1 << 16);
    }

    AW af;
    af.w[0] = aw[0]; af.w[1] = aw[1]; af.w[2] = aw[2]; af.w[3] = aw[3];
#pragma unroll
    for (int dt = 0; dt < 4; ++dt) {
      AW bf;
#pragma unroll
      for (int jp = 0; jp < 4; ++jp) bf.w[jp] = yw[dt][jp];
      acc[dt] = __builtin_amdgcn_mfma_f32_16x16x32_bf16(af.v, bf.v, acc[dt], 0, 0, 0);
    }
  }

  // D[m=quad*4+reg][n=dt*16+nt]: m=rel, n=d -> Z[rel][row][d] (transposed)
  const size_t plane = (size_t)Nn * Dd;
  ushort_t* zb = Z + (size_t)row * Dd + nt;
#pragma unroll
  for (int dt = 0; dt < 4; ++dt)
#pragma unroll
    for (int reg = 0; reg < 4; ++reg)
      zb[(size_t)(quad * 4 + reg) * plane + dt * 16] = f2bf(acc[dt][reg]);
}

// ------- zgemm v4: DMA-staged A via global_load_lds (no VGPR destination) --
// Rounds 2-3 proved the compiler will NOT keep >8 VGPR-destined loads in
// flight (VGPR 40/60, dur pinned at 67us = serialized ~1000cy/load). Fix per
// guide Common-mistake #1: stage A with global_load_lds -- vmcnt-counted DMA,
// zero VGPR results, all 16 loads/wave outstanding, ONE vmcnt(0) stall per
// wave. Each wave stages exactly the 8 rel-planes (16KB) it consumes -> no
// barrier. LDS dest must be linear (lane*16), so the bank swizzle is applied
// on the GLOBAL source address (involution L ^= ((L>>7&7)<<4) within each
// 2KB block) and the same XOR on the ds_read side: 2-way conflicts = free.
__global__ __launch_bounds__(256) void zgemm_k(const ushort_t* __restrict__ Z,
                                               const ushort_t* __restrict__ wl,
                                               ushort_t* __restrict__ embout,
                                               float* __restrict__ finout,
                                               int fin) {
  __shared__ ushort_t zs[2][16][1024];  // [tile_local][rel][16 rows x 64 d] = 64KB
  __shared__ float red[2][64 * 16];     // [tile_local][lane*16+idx] = 8KB
  int wave = threadIdx.x >> 6, lane = threadIdx.x & 63;
  int nt = lane & 15, quad = lane >> 4;
  int tl = wave >> 1, kh = wave & 1;
  int tile = blockIdx.x * 2 + tl;
  if (tile >= NTILE) tile = NTILE - 1;  // dup work; identical values written

  const size_t plane = (size_t)Nn * Dd;

  // --- DMA-stage this wave's 8 rel-planes: 16 x (64 lanes x 16B) ---
  {
    unsigned lswz = ((unsigned)(lane << 4)) ^ ((unsigned)((lane >> 3) << 4));
#pragma unroll
    for (int rr = 0; rr < 8; ++rr) {
      int r = kh * 8 + rr;
      const char* gb = (const char*)(Z + (size_t)r * plane + (size_t)(tile * 16) * Dd);
      char* lb = (char*)&zs[tl][r][0];
#pragma unroll
      for (int h = 0; h < 2; ++h)
        gload_lds16(gb + h * 1024 + lswz, lb + h * 1024);
    }
  }
  asm volatile("s_waitcnt vmcnt(0)" ::: "memory");
  __builtin_amdgcn_sched_barrier(0);

  f32x4 acc[4];
#pragma unroll
  for (int dt = 0; dt < 4; ++dt) acc[dt] = (f32x4){0.f, 0.f, 0.f, 0.f};

  const int swz0 = nt * 128 + (((quad    ) ^ (nt & 7)) << 4);
  const int swz1 = nt * 128 + (((quad + 4) ^ (nt & 7)) << 4);

#pragma unroll
  for (int r8 = 0; r8 < 8; ++r8) {
    int r = kh * 8 + r8;
    const char* ab = (const char*)&zs[tl][r][0];
    short8 a0 = *(const short8*)(ab + swz0);
    short8 a1 = *(const short8*)(ab + swz1);
    short8 b0[4], b1[4];
#pragma unroll
    for (int dt = 0; dt < 4; ++dt) {
      const ushort_t* bp = wl + ((unsigned)r * Dd + dt * 16 + nt) * Dd + quad * 8;
      b0[dt] = *(const short8*)(bp);
      b1[dt] = *(const short8*)(bp + 32);
    }
#pragma unroll
    for (int dt = 0; dt < 4; ++dt) {
      acc[dt] = __builtin_amdgcn_mfma_f32_16x16x32_bf16(a0, b0[dt], acc[dt], 0, 0, 0);
      acc[dt] = __builtin_amdgcn_mfma_f32_16x16x32_bf16(a1, b1[dt], acc[dt], 0, 0, 0);
    }
  }

  // kh==1 waves deposit partials; kh==0 waves combine + epilogue
  if (kh == 1) {
    float* rp = red[tl] + lane * 16;
#pragma unroll
    for (int dt = 0; dt < 4; ++dt)
      *(f32x4*)(rp + dt * 4) = acc[dt];
  }
  __syncthreads();
  if (kh == 1) return;
  {
    const float* rp = red[tl] + lane * 16;
#pragma unroll
    for (int dt = 0; dt < 4; ++dt) {
      f32x4 o = *(const f32x4*)(rp + dt * 4);
#pragma unroll
      for (int reg = 0; reg < 4; ++reg) acc[dt][reg] += o[reg];
    }
  }

  if (!fin) {
#pragma unroll
    for (int dt = 0; dt < 4; ++dt)
#pragma unroll
      for (int reg = 0; reg < 4; ++reg) {
        int row = tile * 16 + quad * 4 + reg;
        embout[(unsigned)row * 64u + dt * 16 + nt] = f2bf(fmaxf(acc[dt][reg], 0.f));
      }
  } else {
    float v[4][4];
#pragma unroll
    for (int dt = 0; dt < 4; ++dt)
#pragma unroll
      for (int reg = 0; reg < 4; ++reg) v[dt][reg] = fmaxf(acc[dt][reg], 0.f);
#pragma unroll
    for (int reg = 0; reg < 4; ++reg) {
      float ss = 0.f;
#pragma unroll
      for (int dt = 0; dt < 4; ++dt) ss = fmaf(v[dt][reg], v[dt][reg], ss);
#pragma unroll
      for (int off = 8; off >= 1; off >>= 1)
        ss += __shfl_xor(ss, off, 64);  // reduce over nt (quad bits preserved)
      float sc = 1.f / fmaxf(sqrtf(ss), 1e-12f);
      int row = tile * 16 + quad * 4 + reg;
#pragma unroll
      for (int dt = 0; dt < 4; ++dt)
        finout[(unsigned)row * 64u + dt * 16 + nt] = v[dt][reg] * sc;
    }
  }
}

extern "C" void kernel_launch(void* const* d_in, const int* in_sizes, int n_in,
                              void* d_out, int out_size, void* d_ws, size_t ws_size,
                              hipStream_t stream) {
  const float* x   = (const float*)d_in[0];
  const float* ent = (const float*)d_in[1];
  const float* rel = (const float*)d_in[2];
  const int* erow  = (const int*)d_in[3];
  const int* ecol  = (const int*)d_in[4];
  const float* ev  = (const float*)d_in[5];
  float* out = (float*)d_out;

  char* p = (char*)d_ws;
  ushort_t* emb_a = (ushort_t*)p;  p += (size_t)Nn * Dd * 2;           // 6.4 MB
  ushort_t* emb_b = (ushort_t*)p;  p += (size_t)Nn * Dd * 2;           // 6.4 MB
  ushort_t* wbf   = (ushort_t*)p;  p += (size_t)2 * Rr * Dd * Dd * 2;  // 256 KB
  ushort_t* Z     = (ushort_t*)p;  p += (size_t)Nn * Rr * Dd * 2;      // 102.4 MB
  uint2* ebkt     = (uint2*)p;     p += (size_t)NE * 8;                // 12.8 MB
  uint2* ed2      = (uint2*)p;     p += (size_t)NE * 8;                // 12.8 MB
  int* cnt        = (int*)p;       p += (size_t)SCTOT * 4;             // 0.8 MB
  int* bsum       = (int*)p;       p += (size_t)(SC_NB + 8) * 4;
  int* cbase      = (int*)p;       p += (size_t)(NBKT + 8) * 4;
  int* offs       = (int*)p;       p += (size_t)(Nn + 8) * 4;          // 0.2 MB

  pre_k<<<INIT_NB + CONVW_NB + CB, 256, 0, stream>>>(
      x, ent, emb_a, rel, wbf, erow, cnt);
  scan1_k<<<SC_NB, 256, 0, stream>>>(cnt, bsum);
  scan2_k<<<1, 1024, 0, stream>>>(bsum);
  scan3_k<<<SC_NB, 256, 0, stream>>>(cnt, bsum, cbase, offs);
  place_k<<<CB, 256, 0, stream>>>(erow, ecol, ev, cnt, ebkt);
  csort_k<<<NBKT, 256, 0, stream>>>(ebkt, cbase, ed2, offs);

  // layer 1
  gather7_k<<<(Nn + 3) / 4, 256, 0, stream>>>(emb_a, offs, ed2, Z);
  zgemm_k<<<(NTILE + 1) / 2, 256, 0, stream>>>(Z, wbf, emb_b, nullptr, 0);
  // layer 2 (+ relu + L2 normalize fused)
  gather7_k<<<(Nn + 3) / 4, 256, 0, stream>>>(emb_b, offs, ed2, Z);
  zgemm_k<<<(NTILE + 1) / 2, 256, 0, stream>>>(Z, wbf + (size_t)Rr * Dd * Dd,
                                               nullptr, out, 1);
}

// Round 5
// 330.159 us; speedup vs baseline: 1.1232x; 1.1232x over previous
//
#include <hip/hip_runtime.h>

#define Nn 50000
#define Rr 16
#define Dd 64
#define Fin 128
#define Ee 100000
#define NE (Rr * Ee)     // 1600000
#define NBKT 782         // ceil(Nn/64) buckets (64 rows each)
#define CB 256           // count/place blocks
#define EPB (NE / CB)    // 6250 edges per block (16 blocks per relation)
#define SCTOT (NBKT * CB)  // 200192 count-matrix entries
#define SC_NB (SCTOT / 256)  // 782 scan blocks
#define NTILE (Nn / 16)  // 3125

typedef __attribute__((ext_vector_type(8))) short short8;
typedef __attribute__((ext_vector_type(4))) float f32x4;
typedef unsigned short ushort_t;

__device__ inline ushort_t f2bf(float x) {
  union { float f; unsigned u; } v; v.f = x;
  unsigned u = v.u;
  return (ushort_t)((u + 0x7FFFu + ((u >> 16) & 1u)) >> 16);  // RNE
}
__device__ inline float bf2f(ushort_t h) {
  union { unsigned u; float f; } v; v.u = ((unsigned)h) << 16; return v.f;
}

// ------- fused pre: MFMA init_gemm + convw + LDS-hist bucket count ---------
#define INIT_TILES 3125            // 50000/16
#define INIT_NB 782                // ceil(3125/4)
#define CONVW_NB 512               // 2*16*64*64 / 256
__global__ __launch_bounds__(256) void pre_k(const float* __restrict__ x,
                                             const float* __restrict__ ent,
                                             ushort_t* __restrict__ emb0,
                                             const float* __restrict__ rel,
                                             ushort_t* __restrict__ wbf,
                                             const int* __restrict__ erow,
                                             int* __restrict__ cnt) {
  __shared__ int lh[NBKT];
  int b = blockIdx.x;
  if (b < INIT_NB) {
    int wave = threadIdx.x >> 6, lane = threadIdx.x & 63;
    int nt = lane & 15, quad = lane >> 4;
    int tile = b * 4 + wave;
    if (tile >= INIT_TILES) return;
    const float* xr = x + ((long)tile * 16 + nt) * Fin + quad * 8;
    short8 afrag[4];
#pragma unroll
    for (int ks = 0; ks < 4; ++ks) {
      float4 p0 = *(const float4*)(xr + ks * 32);
      float4 p1 = *(const float4*)(xr + ks * 32 + 4);
      short8 a;
      a[0] = (short)f2bf(p0.x); a[1] = (short)f2bf(p0.y);
      a[2] = (short)f2bf(p0.z); a[3] = (short)f2bf(p0.w);
      a[4] = (short)f2bf(p1.x); a[5] = (short)f2bf(p1.y);
      a[6] = (short)f2bf(p1.z); a[7] = (short)f2bf(p1.w);
      afrag[ks] = a;
    }
    f32x4 acc[4];
#pragma unroll
    for (int dt = 0; dt < 4; ++dt) acc[dt] = (f32x4){0.f, 0.f, 0.f, 0.f};
#pragma unroll
    for (int ks = 0; ks < 4; ++ks) {
#pragma unroll
      for (int dt = 0; dt < 4; ++dt) {
        short8 bfr;
#pragma unroll
        for (int j = 0; j < 8; ++j)
          bfr[j] = (short)f2bf(ent[(unsigned)(ks * 32 + quad * 8 + j) * Dd + dt * 16 + nt]);
        acc[dt] = __builtin_amdgcn_mfma_f32_16x16x32_bf16(afrag[ks], bfr, acc[dt], 0, 0, 0);
      }
    }
#pragma unroll
    for (int dt = 0; dt < 4; ++dt)
#pragma unroll
      for (int reg = 0; reg < 4; ++reg) {
        int row = tile * 16 + quad * 4 + reg;
        emb0[(unsigned)row * Dd + dt * 16 + nt] = f2bf(acc[dt][reg]);
      }
  } else if (b < INIT_NB + CONVW_NB) {
    int i = (b - INIT_NB) * 256 + threadIdx.x;
    wbf[i] = f2bf(rel[i]);
  } else {
    int blk = b - INIT_NB - CONVW_NB;  // 0..CB-1
    int t = threadIdx.x;
    for (int i = t; i < NBKT; i += 256) lh[i] = 0;
    __syncthreads();
    int r = blk >> 4;
    long gbase = (long)r * Ee + (blk & 15) * EPB;
    for (int i = t; i < EPB; i += 256)
      atomicAdd(&lh[erow[gbase + i] >> 6], 1);  // LDS atomics only
    __syncthreads();
    for (int i = t; i < NBKT; i += 256) cnt[i * CB + blk] = lh[i];
  }
}

// ---------------- parallel scan over cnt[200192], bucket-major --------------
__global__ __launch_bounds__(256) void scan1_k(const int* __restrict__ cnt,
                                               int* __restrict__ bsum) {
  __shared__ int ls[256];
  int t = threadIdx.x;
  ls[t] = cnt[blockIdx.x * 256 + t];
  __syncthreads();
  for (int off = 128; off >= 1; off >>= 1) {
    if (t < off) ls[t] += ls[t + off];
    __syncthreads();
  }
  if (t == 0) bsum[blockIdx.x] = ls[0];
}

__global__ __launch_bounds__(1024) void scan2_k(int* __restrict__ bsum) {
  __shared__ int ls[1024];
  int t = threadIdx.x;
  int v = (t < SC_NB) ? bsum[t] : 0;
  ls[t] = v;
  __syncthreads();
  for (int off = 1; off < 1024; off <<= 1) {
    int x = (t >= off) ? ls[t - off] : 0;
    __syncthreads();
    ls[t] += x;
    __syncthreads();
  }
  if (t < SC_NB) bsum[t] = ls[t] - v;  // exclusive
}

__global__ __launch_bounds__(256) void scan3_k(int* __restrict__ cnt,
                                               const int* __restrict__ bsum,
                                               int* __restrict__ cbase,
                                               int* __restrict__ offs) {
  __shared__ int ls[256];
  int t = threadIdx.x, i = blockIdx.x * 256 + t;
  int v = cnt[i];
  ls[t] = v;
  __syncthreads();
  for (int off = 1; off < 256; off <<= 1) {
    int x = (t >= off) ? ls[t - off] : 0;
    __syncthreads();
    ls[t] += x;
    __syncthreads();
  }
  int excl = ls[t] - v + bsum[blockIdx.x];
  cnt[i] = excl;
  if (t == 0) cbase[blockIdx.x] = excl;
  if (i == SCTOT - 1) { cbase[NBKT] = NE; offs[Nn] = NE; }
}

// ------- place: edges -> bucket-grouped ebkt, LDS cursors, block-private ----
__global__ __launch_bounds__(256) void place_k(const int* __restrict__ erow,
                                               const int* __restrict__ ecol,
                                               const float* __restrict__ ev,
                                               const int* __restrict__ base,
                                               uint2* __restrict__ ebkt) {
  __shared__ int lofs[NBKT];
  int blk = blockIdx.x, t = threadIdx.x;
  for (int i = t; i < NBKT; i += 256) lofs[i] = base[i * CB + blk];
  __syncthreads();
  int r = blk >> 4;
  long gbase = (long)r * Ee + (blk & 15) * EPB;
  for (int i = t; i < EPB; i += 256) {
    long idx = gbase + i;
    int row = erow[idx];
    int pos = atomicAdd(&lofs[row >> 6], 1);
    unsigned vb = f2bf(ev[idx]);
    ebkt[pos] = make_uint2(((unsigned)(row & 63) << 4) | (unsigned)r,
                           (vb << 16) | (unsigned)ecol[idx]);
  }
}

// ------- cluster sort: 64-row cluster -> row-contiguous ed2 + offs ---------
__global__ __launch_bounds__(256) void csort_k(const uint2* __restrict__ ebkt,
                                               const int* __restrict__ cbase,
                                               uint2* __restrict__ ed2,
                                               int* __restrict__ offs) {
  __shared__ int lcnt[64], lstart[64], lcur[64];
  int c = blockIdx.x, t = threadIdx.x;
  int s = cbase[c], e = cbase[c + 1];
  if (t < 64) lcnt[t] = 0;
  __syncthreads();
  for (int i = s + t; i < e; i += 256) atomicAdd(&lcnt[ebkt[i].x >> 4], 1);
  __syncthreads();
  if (t == 0) {
    int run = 0;
    for (int rl = 0; rl < 64; ++rl) {
      int cc = lcnt[rl];
      lstart[rl] = run; lcur[rl] = run; run += cc;
    }
  }
  __syncthreads();
  int nrow = Nn - c * 64; if (nrow > 64) nrow = 64;
  if (t < nrow) offs[c * 64 + t] = s + lstart[t];
  for (int i = s + t; i < e; i += 256) {
    uint2 q = ebkt[i];
    int pos = s + atomicAdd(&lcur[q.x >> 4], 1);
    ed2[pos] = make_uint2(q.x & 15u, q.y);
  }
}

// ---------------- fused_k: gather (4 rows/wave) + in-LDS rel-transform ------
// Deletes the Z global round-trip (102.4MB write + 102.4MB read) that pinned
// zgemm at ~64us across 4 scheduling variants (VGPR burst, sched_barrier,
// DMA staging -- all invariant => delivery of freshly-written cross-XCD data
// is the wall, not issue discipline). One block = one 16-row tile:
//   phase 1: 4 waves x 4 rows gather (inner loop identical to gather7),
//            Z-rows deposited in a 32KB XOR-swizzled LDS tile (pair-packed
//            4B writes, ~4-way conflicts).
//   phase 2: same block transforms the tile: wave = dt quadrant (N-split, no
//            K-reduction), A from LDS (swizzled ds_read_b128, 2 lanes/bank =
//            free), B from L2-resident wbf. relu / L2-normalize epilogue.
// Arithmetic path (bf16 Z, same MFMA shapes) identical to gather7+zgemm.
__global__ __launch_bounds__(256) void fused_k(const ushort_t* __restrict__ emb,
                                               const int* __restrict__ offs,
                                               const uint2* __restrict__ ed2,
                                               const ushort_t* __restrict__ wl,
                                               ushort_t* __restrict__ embout,
                                               float* __restrict__ finout,
                                               int fin) {
  __shared__ ushort_t Zt[16 * 1024];   // 32KB: [row16][rel16][d64] bf16, swizzled
  __shared__ f32x4 ssred[4][4];        // [wave][quad] row-partial sq-sums (fin)
  const int lane = threadIdx.x & 63;
  const int wave = threadIdx.x >> 6;
  const int nt = lane & 15, quad = lane >> 4;
  const int tile = blockIdx.x;

  const int qb = quad << 3;  // this quad's 8 edge slots / k-offset
  const ushort_t* embnt = emb + nt;
  char* ztb = (char*)Zt;
  union AW { unsigned w[4]; short8 v; };

  // ---------------- gather phase: wave owns rows wave*4 .. wave*4+3 ---------
  for (int rr = 0; rr < 4; ++rr) {
    const int rl = wave * 4 + rr;          // row_local 0..15
    const int row = tile * 16 + rl;
    int off_l = (lane < 2) ? offs[row + lane] : 0;
    const int base = __shfl(off_l, 0, 64);
    const int len  = __shfl(off_l, 1, 64) - base;

    f32x4 acc[4];
#pragma unroll
    for (int dt = 0; dt < 4; ++dt) acc[dt] = (f32x4){0.f, 0.f, 0.f, 0.f};

    for (int c = 0; c < len; c += 32) {
      int p = c + (lane & 31);
      uint2 myed = (p < len) ? ed2[base + p] : make_uint2(0u, 0u);  // pad: val=0

      unsigned yw[4][4];  // [dt][pair] packed bf16 pairs for B fragments
      unsigned aw[4];     // packed selector pairs for A fragment
#pragma unroll
      for (int jp = 0; jp < 4; ++jp) {
        unsigned q0 = (unsigned)__shfl((int)myed.y, qb + 2 * jp, 64);
        unsigned q1 = (unsigned)__shfl((int)myed.y, qb + 2 * jp + 1, 64);
        unsigned x0 = (unsigned)__shfl((int)myed.x, qb + 2 * jp, 64);
        unsigned x1 = (unsigned)__shfl((int)myed.x, qb + 2 * jp + 1, 64);
        const ushort_t* e0 = embnt + (q0 & 0xFFFFu) * 64u;
        const ushort_t* e1 = embnt + (q1 & 0xFFFFu) * 64u;
#pragma unroll
        for (int dt = 0; dt < 4; ++dt)
          yw[dt][jp] = (unsigned)e0[dt * 16] | ((unsigned)e1[dt * 16] << 16);
        unsigned t0 = (x0 == (unsigned)nt) ? (q0 >> 16) : 0u;
        unsigned t1 = (x1 == (unsigned)nt) ? (q1 >> 16) : 0u;
        aw[jp] = t0 | (t1 << 16);
      }

      AW af;
      af.w[0] = aw[0]; af.w[1] = aw[1]; af.w[2] = aw[2]; af.w[3] = aw[3];
#pragma unroll
      for (int dt = 0; dt < 4; ++dt) {
        AW bf;
#pragma unroll
        for (int jp = 0; jp < 4; ++jp) bf.w[jp] = yw[dt][jp];
        acc[dt] = __builtin_amdgcn_mfma_f32_16x16x32_bf16(af.v, bf.v, acc[dt], 0, 0, 0);
      }
    }

    // deposit Z-row: D[m=rel=quad*4+reg][n=d=dt*16+nt] -> Zt swizzled.
    // pair-pack (nt, nt^1) into one 4B word; even-nt lanes store.
    const unsigned swz = (unsigned)((rl & 7) << 4);
    const unsigned rb = (unsigned)(rl * 2048 + quad * 512);
#pragma unroll
    for (int dt = 0; dt < 4; ++dt)
#pragma unroll
      for (int reg = 0; reg < 4; ++reg) {
        unsigned hv = (unsigned)f2bf(acc[dt][reg]);
        unsigned pv = (unsigned)__shfl_xor((int)hv, 1, 64);
        if ((nt & 1) == 0) {
          unsigned lg = rb + (unsigned)(reg * 128 + dt * 32 + nt * 2);
          *(unsigned*)(ztb + (lg ^ swz)) = hv | (pv << 16);
        }
      }
  }
  __syncthreads();

  // ------------- transform phase: wave = dt quadrant (cols wave*16..+15) ----
  const int s0 = nt * 2048 + (((quad    ) ^ (nt & 7)) << 4);
  const int s1 = nt * 2048 + (((quad + 4) ^ (nt & 7)) << 4);
  f32x4 accA = (f32x4){0.f, 0.f, 0.f, 0.f};
  f32x4 accB = (f32x4){0.f, 0.f, 0.f, 0.f};
#pragma unroll
  for (int r = 0; r < 16; r += 2) {
    const char* ab0 = ztb + r * 128;
    const char* ab1 = ztb + (r + 1) * 128;
    short8 a00 = *(const short8*)(ab0 + s0);
    short8 a01 = *(const short8*)(ab0 + s1);
    short8 a10 = *(const short8*)(ab1 + s0);
    short8 a11 = *(const short8*)(ab1 + s1);
    const ushort_t* bp0 = wl + (unsigned)(r * Dd + wave * 16 + nt) * Dd + qb;
    const ushort_t* bp1 = wl + (unsigned)((r + 1) * Dd + wave * 16 + nt) * Dd + qb;
    short8 b00 = *(const short8*)(bp0);
    short8 b01 = *(const short8*)(bp0 + 32);
    short8 b10 = *(const short8*)(bp1);
    short8 b11 = *(const short8*)(bp1 + 32);
    accA = __builtin_amdgcn_mfma_f32_16x16x32_bf16(a00, b00, accA, 0, 0, 0);
    accA = __builtin_amdgcn_mfma_f32_16x16x32_bf16(a01, b01, accA, 0, 0, 0);
    accB = __builtin_amdgcn_mfma_f32_16x16x32_bf16(a10, b10, accB, 0, 0, 0);
    accB = __builtin_amdgcn_mfma_f32_16x16x32_bf16(a11, b11, accB, 0, 0, 0);
  }
  f32x4 accO;
#pragma unroll
  for (int reg = 0; reg < 4; ++reg) accO[reg] = accA[reg] + accB[reg];

  // D[m=quad*4+reg = row][n=nt]: out col = wave*16+nt
  if (!fin) {
#pragma unroll
    for (int reg = 0; reg < 4; ++reg) {
      int row = tile * 16 + quad * 4 + reg;
      embout[(unsigned)row * 64u + wave * 16 + nt] = f2bf(fmaxf(accO[reg], 0.f));
    }
  } else {
    float v[4];
    f32x4 ssq;
#pragma unroll
    for (int reg = 0; reg < 4; ++reg) {
      v[reg] = fmaxf(accO[reg], 0.f);
      ssq[reg] = v[reg] * v[reg];
    }
#pragma unroll
    for (int off = 8; off >= 1; off >>= 1)
#pragma unroll
      for (int reg = 0; reg < 4; ++reg)
        ssq[reg] += __shfl_xor(ssq[reg], off, 64);  // reduce over nt bits
    if (nt == 0) ssred[wave][quad] = ssq;
    __syncthreads();
    f32x4 t0 = ssred[0][quad], t1 = ssred[1][quad];
    f32x4 t2 = ssred[2][quad], t3 = ssred[3][quad];
#pragma unroll
    for (int reg = 0; reg < 4; ++reg) {
      float tot = t0[reg] + t1[reg] + t2[reg] + t3[reg];
      float sc = 1.f / fmaxf(sqrtf(tot), 1e-12f);
      int row = tile * 16 + quad * 4 + reg;
      finout[(unsigned)row * 64u + wave * 16 + nt] = v[reg] * sc;
    }
  }
}

extern "C" void kernel_launch(void* const* d_in, const int* in_sizes, int n_in,
                              void* d_out, int out_size, void* d_ws, size_t ws_size,
                              hipStream_t stream) {
  const float* x   = (const float*)d_in[0];
  const float* ent = (const float*)d_in[1];
  const float* rel = (const float*)d_in[2];
  const int* erow  = (const int*)d_in[3];
  const int* ecol  = (const int*)d_in[4];
  const float* ev  = (const float*)d_in[5];
  float* out = (float*)d_out;

  char* p = (char*)d_ws;
  ushort_t* emb_a = (ushort_t*)p;  p += (size_t)Nn * Dd * 2;           // 6.4 MB
  ushort_t* emb_b = (ushort_t*)p;  p += (size_t)Nn * Dd * 2;           // 6.4 MB
  ushort_t* wbf   = (ushort_t*)p;  p += (size_t)2 * Rr * Dd * Dd * 2;  // 256 KB
  uint2* ebkt     = (uint2*)p;     p += (size_t)NE * 8;                // 12.8 MB
  uint2* ed2      = (uint2*)p;     p += (size_t)NE * 8;                // 12.8 MB
  int* cnt        = (int*)p;       p += (size_t)SCTOT * 4;             // 0.8 MB
  int* bsum       = (int*)p;       p += (size_t)(SC_NB + 8) * 4;
  int* cbase      = (int*)p;       p += (size_t)(NBKT + 8) * 4;
  int* offs       = (int*)p;       p += (size_t)(Nn + 8) * 4;          // 0.2 MB

  pre_k<<<INIT_NB + CONVW_NB + CB, 256, 0, stream>>>(
      x, ent, emb_a, rel, wbf, erow, cnt);
  scan1_k<<<SC_NB, 256, 0, stream>>>(cnt, bsum);
  scan2_k<<<1, 1024, 0, stream>>>(bsum);
  scan3_k<<<SC_NB, 256, 0, stream>>>(cnt, bsum, cbase, offs);
  place_k<<<CB, 256, 0, stream>>>(erow, ecol, ev, cnt, ebkt);
  csort_k<<<NBKT, 256, 0, stream>>>(ebkt, cbase, ed2, offs);

  // layer 1 (gather + transform fused; no Z round-trip)
  fused_k<<<NTILE, 256, 0, stream>>>(emb_a, offs, ed2, wbf, emb_b, nullptr, 0);
  // layer 2 (+ relu + L2 normalize fused)
  fused_k<<<NTILE, 256, 0, stream>>>(emb_b, offs, ed2,
                                     wbf + (size_t)Rr * Dd * Dd, nullptr, out, 1);
}